// Round 3
// baseline (11211.311 us; speedup 1.0000x reference)
//
#include <hip/hip_runtime.h>
#include <hip/hip_bf16.h>
#include <hip/hip_fp16.h>

typedef unsigned int u32;
typedef unsigned short u16;
typedef __attribute__((ext_vector_type(4))) float f32x4;
typedef __attribute__((ext_vector_type(8))) _Float16 h16x8;

#define NL2E  (-1.4426950408889634f)
#define P2L2E ( 2.8853900817779268f)

__device__ __forceinline__ u16 f2h(float f) {
  _Float16 h = (_Float16)f;                       // v_cvt_f16_f32, RNE
  return __builtin_bit_cast(u16, h);
}
__device__ __forceinline__ float h2f(u16 u) {
  return (float)__builtin_bit_cast(_Float16, u);
}
__device__ __forceinline__ void gload16(const void* g, void* l) {
  __builtin_amdgcn_global_load_lds((const __attribute__((address_space(1))) u32*)g,
                                   (__attribute__((address_space(3))) u32*)l, 16, 0, 0);
}

// ---------------- fp32 -> fp16 conversions ----------------
__global__ void convh_k(const float* __restrict__ s, u16* __restrict__ d, int n4) {
  int i = blockIdx.x * 256 + threadIdx.x;
  if (i < n4) {
    float4 f = ((const float4*)s)[i];
    ushort4 u;
    u.x = f2h(f.x); u.y = f2h(f.y); u.z = f2h(f.z); u.w = f2h(f.w);
    ((ushort4*)d)[i] = u;
  }
}

// hi = fp16(v), lo = fp16(v - hi): fp16-pair, effective ~fp22
__global__ void convpair_k(const float* __restrict__ s, u16* __restrict__ dh,
                           u16* __restrict__ dl, int n4) {
  int i = blockIdx.x * 256 + threadIdx.x;
  if (i < n4) {
    float4 f = ((const float4*)s)[i];
    ushort4 uh, ul;
    uh.x = f2h(f.x); ul.x = f2h(f.x - h2f(uh.x));
    uh.y = f2h(f.y); ul.y = f2h(f.y - h2f(uh.y));
    uh.z = f2h(f.z); ul.z = f2h(f.z - h2f(uh.z));
    uh.w = f2h(f.w); ul.w = f2h(f.w - h2f(uh.w));
    ((ushort4*)dh)[i] = uh;
    ((ushort4*)dl)[i] = ul;
  }
}

// badd[lay][1536] = bih + (gate<512 ? bhh : 0)  (bhh_n stays inside r-multiply)
__global__ void badd_k(const float* __restrict__ bih0, const float* __restrict__ bhh0,
                       const float* __restrict__ bih12, const float* __restrict__ bhh12,
                       float* __restrict__ badd) {
  int i = blockIdx.x * 256 + threadIdx.x;
  if (i < 4608) {
    int lay = i / 1536, r = i % 1536;
    int dd = r / 768, gg = r % 768;
    float bi = lay == 0 ? bih0[dd * 768 + gg] : bih12[((lay - 1) * 2 + dd) * 768 + gg];
    float bh = lay == 0 ? bhh0[dd * 768 + gg] : bhh12[((lay - 1) * 2 + dd) * 768 + gg];
    badd[i] = bi + (gg < 512 ? bh : 0.f);
  }
}

// ---------------- xg GEMM: D[n][m] = W[n][:] . (Bhi+Blo)[m][:] + badd, fp32 out ----
// A: [1536][K] fp16. B pair rows m = tl*64+b. Out layout per (d,tl,bg8) 24KB block:
// [3 gates][16 j][32 slots=(g*8+m8)][4 floats] -> float off = blk*6144 + q*2048 + j*128 + s*4
template<int K>
__global__ __launch_bounds__(256, 2) void gemm_k(
    const u16* __restrict__ A, const u16* __restrict__ Bh,
    const u16* __restrict__ Bl, const float* __restrict__ badd_l,
    float* __restrict__ xg, int t0)
{
  __shared__ __attribute__((aligned(16))) char sm[49152];  // A 16K | Bhi 16K | Blo 16K
  const int tid = threadIdx.x;
  const int w = tid >> 6, l = tid & 63;
  const int g = l >> 4, lm = l & 15;
  const int wr = w >> 1, wc = w & 1;

  int bx = blockIdx.x;
  int wg = (bx & 7) * 96 + (bx >> 3);       // XCD-bijective (768 % 8 == 0)
  int nb = wg % 12, mb = wg / 12;

  u32 offA[4], offB[4];
#pragma unroll
  for (int c = 0; c < 4; ++c) {
    int x = c * 4096 + tid * 16;
    int row = x >> 7;
    int blog = (x - row * 16) & 127;        // rotation swizzle (16B per row, mod 128)
    offA[c] = (u32)((nb * 128 + row) * (K * 2) + blog);
    int m = mb * 128 + row;                 // m = tl*64 + b
    int b2 = m & 63, tl2 = m >> 6;
    if constexpr (K == 64) offB[c] = (u32)((b2 * 1024 + t0 + tl2) * 128 + blog);
    else                   offB[c] = (u32)((b2 * 128 + tl2) * 1024 + blog);
  }
  u32 aoff[4][2], boff[4][2];
#pragma unroll
  for (int i = 0; i < 4; ++i) {
    int rowA = wr * 64 + i * 16 + lm;
    int rowB = wc * 64 + i * 16 + lm;
#pragma unroll
    for (int kk = 0; kk < 2; ++kk) {
      aoff[i][kk] = rowA * 128 + ((g * 16 + kk * 64 + rowA * 16) & 127);
      boff[i][kk] = rowB * 128 + ((g * 16 + kk * 64 + rowB * 16) & 127);
    }
  }

  f32x4 acc[4][4];
#pragma unroll
  for (int a = 0; a < 4; ++a)
#pragma unroll
    for (int c = 0; c < 4; ++c) acc[a][c] = (f32x4){0.f, 0.f, 0.f, 0.f};

  const char* Ac = (const char*)A;
  const char* Bhc = (const char*)Bh;
  const char* Blc = (const char*)Bl;

#pragma unroll 1
  for (int ki = 0; ki < K / 64; ++ki) {
    __syncthreads();
#pragma unroll
    for (int c = 0; c < 4; ++c) {
      gload16(Ac + offA[c], sm + c * 4096 + w * 1024);
      gload16(Bhc + offB[c], sm + 16384 + c * 4096 + w * 1024);
      gload16(Blc + offB[c], sm + 32768 + c * 4096 + w * 1024);
      offA[c] += 128; offB[c] += 128;
    }
    __syncthreads();
#pragma unroll
    for (int kk = 0; kk < 2; ++kk) {
      h16x8 af[4], bh4[4], bl4[4];
#pragma unroll
      for (int a = 0; a < 4; ++a) af[a] = *(const h16x8*)(sm + aoff[a][kk]);
#pragma unroll
      for (int c = 0; c < 4; ++c) bh4[c] = *(const h16x8*)(sm + 16384 + boff[c][kk]);
#pragma unroll
      for (int c = 0; c < 4; ++c) bl4[c] = *(const h16x8*)(sm + 32768 + boff[c][kk]);
#pragma unroll
      for (int a = 0; a < 4; ++a)
#pragma unroll
        for (int c = 0; c < 4; ++c) {
          acc[a][c] = __builtin_amdgcn_mfma_f32_16x16x32_f16(af[a], bh4[c], acc[a][c], 0, 0, 0);
          acc[a][c] = __builtin_amdgcn_mfma_f32_16x16x32_f16(af[a], bl4[c], acc[a][c], 0, 0, 0);
        }
    }
  }

  float4 bd[4];
#pragma unroll
  for (int a = 0; a < 4; ++a)
    bd[a] = *(const float4*)(badd_l + nb * 128 + (wr * 4 + a) * 16 + 4 * g);

#pragma unroll
  for (int a = 0; a < 4; ++a) {
    int n_t = nb * 8 + wr * 4 + a;          // 0..95
    int dd = n_t >= 48 ? 1 : 0;
    int rem = n_t - 48 * dd;
    int q = rem >> 4, j = rem & 15;
#pragma unroll
    for (int c = 0; c < 4; ++c) {
      int m_t = mb * 8 + wc * 4 + c;        // 0..511
      int tl = m_t >> 2, bg16 = m_t & 3;
      int bib = l & 15;
      int bg8 = bg16 * 2 + (bib >> 3);
      int s = g * 8 + (bib & 7);
      size_t blk = (size_t)((dd * 128 + tl) * 8 + bg8);
      float4 v = make_float4(acc[a][c][0] + bd[a].x, acc[a][c][1] + bd[a].y,
                             acc[a][c][2] + bd[a].z, acc[a][c][3] + bd[a].w);
      *(float4*)(xg + blk * 6144 + q * 2048 + j * 128 + s * 4) = v;
    }
  }
}

// ---------------- GRU recurrence: 16 WGs = (bg8 x dir), incremental-Delta scheme ----
// State: G[j][q] fp32 accum (gh = Whh . h_sent, G_n seeded with bhh_n), hs fp32.
// Per step: gates from G + xg(fp32); qd = fp16(h - hs); hs += qd; G += Whh . qd (MFMA).
// LDS: xg dbuf 2x24KB @0 | Delta dbuf 2x4KB @49152. One barrier/step.
__global__ __launch_bounds__(256, 1) void recur_k(
    const char* __restrict__ xg, const u16* __restrict__ whh,
    const float* __restrict__ bhh, u16* __restrict__ yhi,
    u16* __restrict__ ylo, u16* __restrict__ y16,
    float* __restrict__ Gst, float* __restrict__ hst, int t0)
{
  __shared__ __attribute__((aligned(16))) char sm[57344];
  const int bid = blockIdx.x;
  const int d = bid & 1, bg8 = bid >> 1;
  const int tid = threadIdx.x;
  const int w = tid >> 6, l = tid & 63;
  const int g = l >> 4, m8 = l & 7;
  const bool valid = (l & 15) < 8;
  const int batch = bg8 * 8 + m8;

  const u16* wp = whh + (size_t)d * 196608;
  // stationary Whh fp16 A-frags: lane holds Whh[q*256+(4w+j)*16+(l&15)][kk*32+g*8+e]
  h16x8 bfr[4][3][8];
#pragma unroll
  for (int j = 0; j < 4; ++j)
#pragma unroll
    for (int q = 0; q < 3; ++q)
#pragma unroll
      for (int kk = 0; kk < 8; ++kk)
        bfr[j][q][kk] = *(const h16x8*)(wp + (size_t)(q * 256 + (4 * w + j) * 16 + (l & 15)) * 256
                                        + kk * 32 + g * 8);

  f32x4 G[4][3];
  f32x4 hs[4];
  if (t0 == 0) {
#pragma unroll
    for (int j = 0; j < 4; ++j) {
      G[j][0] = (f32x4){0.f, 0.f, 0.f, 0.f};
      G[j][1] = (f32x4){0.f, 0.f, 0.f, 0.f};
      G[j][2] = *(const f32x4*)(bhh + d * 768 + 512 + (4 * w + j) * 16 + 4 * g);
      hs[j] = (f32x4){0.f, 0.f, 0.f, 0.f};
    }
  } else {
    const f32x4* gsrc = (const f32x4*)(Gst + (size_t)(bid * 256 + tid) * 48);
#pragma unroll
    for (int j = 0; j < 4; ++j) {
      G[j][0] = gsrc[j * 3]; G[j][1] = gsrc[j * 3 + 1]; G[j][2] = gsrc[j * 3 + 2];
    }
    const f32x4* hsrc = (const f32x4*)(hst + (size_t)(bid * 256 + tid) * 16);
#pragma unroll
    for (int j = 0; j < 4; ++j) hs[j] = hsrc[j];
  }

  const int xrd = (g * 8 + m8) * 16;        // slot within j-block
  const int drd = m8 * 64 + g * 16;         // Delta frag read
  int dwr[4];
#pragma unroll
  for (int j = 0; j < 4; ++j) {
    int k0 = 64 * w + 16 * j + 4 * g;
    dwr[j] = (k0 >> 5) * 512 + m8 * 64 + (((k0 & 31) >> 3)) * 16 + ((k0 & 7) << 1);
  }
  const char* xb = xg + (size_t)(d * 1024 + bg8) * 24576;
  u16* y16b = y16 ? (y16 + (size_t)(batch * 1024 + t0) * 512 + d * 256 + 64 * w + 4 * g) : (u16*)0;
  u16* yhb = yhi + (size_t)(batch * 128) * 512 + d * 256 + 64 * w + 4 * g;
  u16* ylb = ylo + (size_t)(batch * 128) * 512 + d * 256 + 64 * w + 4 * g;

  // stage tl=0 -> buf0 (layout is linear copy of the 24KB block)
#pragma unroll
  for (int c = 0; c < 6; ++c)
    gload16(xb + c * 4096 + tid * 16, sm + c * 4096 + w * 1024);
  __syncthreads();

#pragma unroll 1
  for (int tl = 0; tl < 128; ++tl) {
    const int P = tl & 1;
    const char* smx = sm + P * 24576;
    if (tl < 127) {                          // prefetch next xg block
      const char* src = xb + (size_t)(tl + 1) * 196608;
      char* dst = sm + (P ^ 1) * 24576 + w * 1024;
#pragma unroll
      for (int c = 0; c < 6; ++c)
        gload16(src + c * 4096 + tid * 16, dst + c * 4096);
    }
    // ---- gate phase: pre = G + xg; h; qd; hs update; Delta write ----
#pragma unroll
    for (int j = 0; j < 4; ++j) {
      const int jo = (4 * w + j) * 512 + xrd;
      f32x4 xr = *(const f32x4*)(smx + jo);
      f32x4 xz = *(const f32x4*)(smx + 8192 + jo);
      f32x4 xn = *(const f32x4*)(smx + 16384 + jo);
      u16 qd4[4];
#pragma unroll
      for (int e = 0; e < 4; ++e) {
        float pr = G[j][0][e] + xr[e];
        float pz = G[j][1][e] + xz[e];
        float r = __builtin_amdgcn_rcpf(1.f + __builtin_amdgcn_exp2f(pr * NL2E));
        float z = __builtin_amdgcn_rcpf(1.f + __builtin_amdgcn_exp2f(pz * NL2E));
        float np = xn[e] + r * G[j][2][e];
        float nt = 1.f - 2.f * __builtin_amdgcn_rcpf(1.f + __builtin_amdgcn_exp2f(np * P2L2E));
        float hp = hs[j][e];
        float h = nt + z * (hp - nt);
        qd4[e] = f2h(h - hp);
        hs[j][e] = hp + h2f(qd4[e]);        // error-feedback state
      }
      if (valid)
        *(uint2*)(sm + 49152 + P * 4096 + dwr[j]) =
            make_uint2((u32)qd4[0] | ((u32)qd4[1] << 16),
                       (u32)qd4[2] | ((u32)qd4[3] << 16));
    }
    __syncthreads();
    // ---- overlapped phase: y-pair stores (from hs) + MFMA G += Whh . qd ----
#pragma unroll
    for (int j = 0; j < 4; ++j) {
      u16 hh4[4], hl4[4];
#pragma unroll
      for (int e = 0; e < 4; ++e) {
        hh4[e] = f2h(hs[j][e]);
        hl4[e] = f2h(hs[j][e] - h2f(hh4[e]));
      }
      if (valid) {
        uint2 hv = make_uint2((u32)hh4[0] | ((u32)hh4[1] << 16),
                              (u32)hh4[2] | ((u32)hh4[3] << 16));
        uint2 lv = make_uint2((u32)hl4[0] | ((u32)hl4[1] << 16),
                              (u32)hl4[2] | ((u32)hl4[3] << 16));
        *(uint2*)(yhb + j * 16) = hv;
        *(uint2*)(ylb + j * 16) = lv;
        if (y16b) *(uint2*)(y16b + j * 16) = hv;
      }
    }
    yhb += 512; ylb += 512; if (y16b) y16b += 512;
#pragma unroll
    for (int kk = 0; kk < 8; ++kk) {
      h16x8 cur = *(const h16x8*)(sm + 49152 + P * 4096 + kk * 512 + drd);
#pragma unroll
      for (int j = 0; j < 4; ++j) {
        G[j][0] = __builtin_amdgcn_mfma_f32_16x16x32_f16(bfr[j][0][kk], cur, G[j][0], 0, 0, 0);
        G[j][1] = __builtin_amdgcn_mfma_f32_16x16x32_f16(bfr[j][1][kk], cur, G[j][1], 0, 0, 0);
        G[j][2] = __builtin_amdgcn_mfma_f32_16x16x32_f16(bfr[j][2][kk], cur, G[j][2], 0, 0, 0);
      }
    }
  }
  // save chunk state
  f32x4* gdst = (f32x4*)(Gst + (size_t)(bid * 256 + tid) * 48);
#pragma unroll
  for (int j = 0; j < 4; ++j) {
    gdst[j * 3] = G[j][0]; gdst[j * 3 + 1] = G[j][1]; gdst[j * 3 + 2] = G[j][2];
  }
  f32x4* hdst = (f32x4*)(hst + (size_t)(bid * 256 + tid) * 16);
#pragma unroll
  for (int j = 0; j < 4; ++j) hdst[j] = hs[j];
}

// ---------------- gather last timestep + classifier (fp16 y) ----------------
__global__ void cls_k(const u16* __restrict__ y2, const int* __restrict__ sl,
                      const float* __restrict__ Wc, const float* __restrict__ bc,
                      float* __restrict__ out) {
  int b = blockIdx.x * 8 + (threadIdx.x >> 5);
  int cc = threadIdx.x & 31;
  int t = sl[b] - 1; t = t < 0 ? 0 : (t > 1023 ? 1023 : t);
  const u16* hr = y2 + (size_t)(b * 1024 + t) * 512;
  float s = 0.f;
  for (int k = 0; k < 512; k += 4) {
    ushort4 hv = *(const ushort4*)(hr + k);
    float4 wv = *(const float4*)(Wc + cc * 512 + k);
    s += h2f(hv.x) * wv.x + h2f(hv.y) * wv.y + h2f(hv.z) * wv.z + h2f(hv.w) * wv.w;
  }
  out[b * 32 + cc] = s + bc[cc];
}

// ---------------- host ----------------
extern "C" void kernel_launch(void* const* d_in, const int* in_sizes, int n_in,
                              void* d_out, int out_size, void* d_ws, size_t ws_size,
                              hipStream_t stream)
{
  const float* x     = (const float*)d_in[0];
  const int*   sl    = (const int*)d_in[1];
  const float* Wih0  = (const float*)d_in[2];
  const float* Whh0  = (const float*)d_in[3];
  const float* bih0  = (const float*)d_in[4];
  const float* bhh0  = (const float*)d_in[5];
  const float* Wih12 = (const float*)d_in[6];
  const float* Whh12 = (const float*)d_in[7];
  const float* bih12 = (const float*)d_in[8];
  const float* bhh12 = (const float*)d_in[9];
  const float* Wc    = (const float*)d_in[10];
  const float* bc    = (const float*)d_in[11];
  float* out = (float*)d_out;

  char* ws = (char*)d_ws;
  float* xg    = (float*)(ws);                 //  50,331,648
  u16* yhi0    = (u16*)(ws + 50331648);        //   8,388,608 (pair chunk, lay0 / lay2 sink)
  u16* ylo0    = (u16*)(ws + 58720256);        //   8,388,608
  u16* yhi1    = (u16*)(ws + 67108864);        //   8,388,608 (lay1)
  u16* ylo1    = (u16*)(ws + 75497472);        //   8,388,608
  u16* y16     = (u16*)(ws + 83886080);        //  67,108,864 (final layer, full T)
  u16* xhi     = (u16*)(ws + 150994944);       //   8,388,608
  u16* xlo     = (u16*)(ws + 159383552);       //   8,388,608
  u16* wih0h   = (u16*)(ws + 167772160);       //     196,608
  u16* wih12h  = (u16*)(ws + 167968768);       //   3,145,728
  u16* whhh    = (u16*)(ws + 171114496);       //   2,359,296  [3][2][768][256] fp16
  float* badd  = (float*)(ws + 173473792);     //      18,432
  float* Gws   = (float*)(ws + 173492224);     //   2,359,296  (3 x 16 x 256 x 48 f32)
  float* hsws  = (float*)(ws + 175851520);     //     786,432  (3 x 16 x 256 x 16 f32)

  convpair_k<<<4096, 256, 0, stream>>>(x, xhi, xlo, 1048576);
  convh_k<<<96,   256, 0, stream>>>(Wih0, wih0h, 24576);
  convh_k<<<1536, 256, 0, stream>>>(Wih12, wih12h, 393216);
  convh_k<<<384,  256, 0, stream>>>(Whh0, whhh, 98304);
  convh_k<<<768,  256, 0, stream>>>(Whh12, whhh + 393216, 196608);
  badd_k<<<18,    256, 0, stream>>>(bih0, bhh0, bih12, bhh12, badd);

  const int GN = 16 * 256 * 48, HN = 16 * 256 * 16;
  for (int ch = 0; ch < 8; ++ch) {
    int t0 = ch * 128;
    gemm_k<64><<<768, 256, 0, stream>>>(wih0h, xhi, xlo, badd, xg, t0);
    recur_k<<<16, 256, 0, stream>>>((const char*)xg, whhh, bhh0,
                                    yhi0, ylo0, (u16*)0, Gws, hsws, t0);
    gemm_k<512><<<768, 256, 0, stream>>>(wih12h, yhi0, ylo0, badd + 1536, xg, t0);
    recur_k<<<16, 256, 0, stream>>>((const char*)xg, whhh + 393216, bhh12,
                                    yhi1, ylo1, (u16*)0, Gws + GN, hsws + HN, t0);
    gemm_k<512><<<768, 256, 0, stream>>>(wih12h + 786432, yhi1, ylo1, badd + 3072, xg, t0);
    recur_k<<<16, 256, 0, stream>>>((const char*)xg, whhh + 786432, bhh12 + 1536,
                                    yhi0, ylo0, y16, Gws + 2 * GN, hsws + 2 * HN, t0);
  }
  cls_k<<<8, 256, 0, stream>>>(y16, sl, Wc, bc, out);
}